// Round 4
// baseline (151.850 us; speedup 1.0000x reference)
//
#include <hip/hip_runtime.h>
#include <math.h>

#define Bn 4
#define Tn 4096
#define En 256
#define An 64

typedef __attribute__((ext_vector_type(8))) short short8;
typedef __attribute__((ext_vector_type(8))) __bf16 bf16x8;
typedef __attribute__((ext_vector_type(4))) float f32x4;
typedef __attribute__((ext_vector_type(4))) int int4v;
typedef __attribute__((ext_vector_type(4))) short short4v;

__device__ __forceinline__ f32x4 mfma16(short8 a, short8 b, f32x4 c) {
    return __builtin_amdgcn_mfma_f32_16x16x32_bf16(
        __builtin_bit_cast(bf16x8, a), __builtin_bit_cast(bf16x8, b), c, 0, 0, 0);
}
__device__ __forceinline__ unsigned short f2bf(float x) {   // RNE fp32->bf16
    unsigned int u = __builtin_bit_cast(unsigned int, x);
    u += 0x7fffu + ((u >> 16) & 1u);
    return (unsigned short)(u >> 16);
}
__device__ __forceinline__ float bf2f(unsigned short h) {
    return __builtin_bit_cast(float, (unsigned int)h << 16);
}
__device__ __forceinline__ unsigned int packbf2(float lo, float hi) {
    return (unsigned int)f2bf(lo) | ((unsigned int)f2bf(hi) << 16);
}

// ---------------------------------------------------------------------------
// Kernel 0: transpose W[e][a] fp32 -> W_t[m][a][e] bf16.  grid (3, 16).
// ---------------------------------------------------------------------------
__global__ __launch_bounds__(256) void prep_kernel(
    const float* __restrict__ Wq, const float* __restrict__ Wk, const float* __restrict__ Wv,
    unsigned short* __restrict__ W_t)
{
    const int m  = blockIdx.x;
    const int es = blockIdx.y;          // e-slice of 16
    const float* __restrict__ W = (m == 0) ? Wq : (m == 1 ? Wk : Wv);
    __shared__ unsigned short tr[64][18];
    const int tid = threadIdx.x;
    {
        const int e_l = tid >> 4;             // 0..15
        const int a4  = (tid & 15) * 4;
        float4 w = *(const float4*)&W[(size_t)(es * 16 + e_l) * An + a4];
        tr[a4 + 0][e_l] = f2bf(w.x);
        tr[a4 + 1][e_l] = f2bf(w.y);
        tr[a4 + 2][e_l] = f2bf(w.z);
        tr[a4 + 3][e_l] = f2bf(w.w);
    }
    __syncthreads();
    {
        const int a  = tid >> 2;              // 0..63
        const int eo = (tid & 3) * 4;         // 0..12
        short4v v = { (short)tr[a][eo], (short)tr[a][eo + 1],
                      (short)tr[a][eo + 2], (short)tr[a][eo + 3] };
        *(short4v*)&W_t[(size_t)(m * 64 + a) * En + es * 16 + eo] = v;
    }
}

// ---------------------------------------------------------------------------
// Kernel 1: fused QKV projection, bf16 MFMA.  grid 512: blockIdx.x>>1 = 64-row
// block, &1 = column half (6 n-tiles each).  Wave w owns rows w*16..+15.
// Outputs: q bf16 [b][t][a] pre-scaled by 0.125*log2(e)  (exp2-domain softmax),
//          k bf16 [b][t][a],  v_t bf16 [b][a][t].
// ---------------------------------------------------------------------------
__global__ __launch_bounds__(256, 2) void proj_kernel(
    const float* __restrict__ emb, const unsigned short* __restrict__ W_t,
    const float* __restrict__ bq, const float* __restrict__ bk, const float* __restrict__ bv,
    unsigned short* __restrict__ q, unsigned short* __restrict__ k, unsigned short* __restrict__ v_t)
{
    const int tid  = threadIdx.x;
    const int wave = tid >> 6, lane = tid & 63, quad = lane >> 4, l15 = lane & 15;
    const int rb    = blockIdx.x >> 1;
    const int half  = blockIdx.x & 1;
    const int row0  = rb * 64;              // global row in [0, B*T)
    const int b     = row0 >> 12;
    const int trow0 = row0 & 4095;

    __shared__ unsigned short vtr[64 * 72];

    // A-fragments: emb rows (fp32 -> bf16), A[m=l15][k=quad*8+j]
    short8 A[8];
    {
        const float* erow = emb + (size_t)(row0 + wave * 16 + l15) * En;
#pragma unroll
        for (int c = 0; c < 8; c++) {
            const float* p = erow + c * 32 + quad * 8;
            float4 f0 = *(const float4*)p;
            float4 f1 = *(const float4*)(p + 4);
            A[c] = (short8){(short)f2bf(f0.x), (short)f2bf(f0.y), (short)f2bf(f0.z), (short)f2bf(f0.w),
                            (short)f2bf(f1.x), (short)f2bf(f1.y), (short)f2bf(f1.z), (short)f2bf(f1.w)};
        }
    }

    f32x4 acc[6];
#pragma unroll
    for (int i = 0; i < 6; i++) acc[i] = (f32x4){0.f, 0.f, 0.f, 0.f};

#pragma unroll
    for (int i = 0; i < 6; i++) {
        const int nt = half * 6 + i;
        const unsigned short* wb =
            W_t + (size_t)((nt >> 2) * 64 + (nt & 3) * 16 + l15) * En + quad * 8;
#pragma unroll
        for (int c = 0; c < 8; c++) {
            short8 bf = *(const short8*)(wb + c * 32);
            acc[i] = mfma16(A[c], bf, acc[i]);
        }
    }

    const float QS = 0.125f * 1.4426950408889634f;   // 1/sqrt(A) * log2(e)
#pragma unroll
    for (int i = 0; i < 6; i++) {
        const int nt = half * 6 + i;
        const int m  = nt >> 2;
        const int al = (nt & 3) * 16 + l15;
        const float bsv = ((m == 0) ? bq : (m == 1) ? bk : bv)[al];
#pragma unroll
        for (int rg = 0; rg < 4; rg++) {
            const int row_l = wave * 16 + quad * 4 + rg;   // C/D: row=quad*4+reg, col=l15
            const float val = acc[i][rg] + bsv;
            if (m == 0)      q[(size_t)(row0 + row_l) * An + al] = f2bf(val * QS);
            else if (m == 1) k[(size_t)(row0 + row_l) * An + al] = f2bf(val);
            else             vtr[al * 72 + row_l] = f2bf(val);
        }
    }
    if (half == 1) {
        __syncthreads();
        // flush V^T tile: v_t[b][a][t]
        const int a  = tid >> 2;
        const int tg = (tid & 3) * 16;
        unsigned short* dst = v_t + (size_t)(b * 64 + a) * Tn + trow0 + tg;
        *(short8*)dst       = *(const short8*)&vtr[a * 72 + tg];
        *(short8*)(dst + 8) = *(const short8*)&vtr[a * 72 + tg + 8];
    }
}

// ---------------------------------------------------------------------------
// Kernel 2: flash attention, bf16 MFMA.  NO barriers; waves fully independent
// and all EQUAL LENGTH: each wave processes the complementary q-tile pair
// (p, 127-p), kv-striped by S.  grid (16*S, 4).
// wave-unit wu = blockIdx.x*4+wave in [0, 64*S): p = wu>>lgS, s = wu&(S-1).
// S^T = K Q^T orientation; softmax in exp2 domain; P transpose via shuffles.
// Partials: Opart[(b*128+qt32)*S+s] = bf16 [32 qrow][64 a]; ml = m,l per row.
// ---------------------------------------------------------------------------
__global__ __launch_bounds__(256, 3) void flash_kernel(
    const unsigned short* __restrict__ q, const unsigned short* __restrict__ k,
    const unsigned short* __restrict__ v_t,
    unsigned short* __restrict__ Opart, float* __restrict__ ml,
    int S, int lgS)
{
    const int b    = blockIdx.y;
    const int tid  = threadIdx.x;
    const int wave = tid >> 6, lane = tid & 63, quad = lane >> 4, l15 = lane & 15;
    const int wu   = blockIdx.x * 4 + wave;
    const int p    = wu >> lgS;
    const int s    = wu & (S - 1);

    __shared__ unsigned short tr[4][32 * 72];   // per-wave O transpose scratch
    unsigned short* tw = tr[wave];

    const unsigned short* kb0 = k   + ((size_t)b << 12) * An;
    const unsigned short* vb0 = v_t + (size_t)b * An * Tn;

#pragma unroll 1
    for (int tile = 0; tile < 2; tile++) {
        const int qt32  = tile ? (127 - p) : p;
        const int qrow0 = qt32 * 32;
        const int tmax  = qt32 >> 1;

        // persistent Q B-fragments: B[k=a][n=qrow], group g = qcols 16g..16g+15
        short8 qB[2][2];
        {
            const unsigned short* qb = q + (((size_t)b << 12) + qrow0) * An;
#pragma unroll
            for (int g = 0; g < 2; g++)
#pragma unroll
                for (int c = 0; c < 2; c++)
                    qB[g][c] = *(const short8*)(qb + (size_t)(16 * g + l15) * An + c * 32 + quad * 8);
        }

        float m_s[2] = {-__builtin_inff(), -__builtin_inff()};
        float l_s[2] = {0.f, 0.f};
        f32x4 O[4][2];
#pragma unroll
        for (int nt = 0; nt < 4; nt++)
#pragma unroll
            for (int g = 0; g < 2; g++) O[nt][g] = (f32x4){0.f, 0.f, 0.f, 0.f};

        for (int t = s; t <= tmax; t += S) {
            // ---- K A-fragments straight from cache ----
            short8 KA[4][2];
            {
                const unsigned short* kb = kb0 + (size_t)t * 64 * An;
#pragma unroll
                for (int nt = 0; nt < 4; nt++)
#pragma unroll
                    for (int c = 0; c < 2; c++)
                        KA[nt][c] = *(const short8*)(kb + (size_t)(nt * 16 + l15) * An + c * 32 + quad * 8);
            }

            // ---- S^T = K Q^T : 16 MFMA.  S^T[kv=quad*4+rg(+16nt)][qrow=16g+l15]
            f32x4 St[4][2];
#pragma unroll
            for (int nt = 0; nt < 4; nt++)
#pragma unroll
                for (int g = 0; g < 2; g++) {
                    f32x4 acc = (f32x4){0.f, 0.f, 0.f, 0.f};
                    acc = mfma16(KA[nt][0], qB[g][0], acc);
                    acc = mfma16(KA[nt][1], qB[g][1], acc);
                    St[nt][g] = acc;
                }

            // ---- V^T A-fragments (issue early; consumed after softmax) ----
            short8 VA[4][2];
            {
                const unsigned short* vb = vb0 + (size_t)t * 64;
#pragma unroll
                for (int nt = 0; nt < 4; nt++)
#pragma unroll
                    for (int c = 0; c < 2; c++)
                        VA[nt][c] = *(const short8*)(vb + (size_t)(nt * 16 + l15) * Tn + c * 32 + quad * 8);
            }

            // ---- causal mask on the diagonal tile ----
            if (t == tmax) {
                const int kvb = t * 64 + quad * 4;
#pragma unroll
                for (int nt = 0; nt < 4; nt++)
#pragma unroll
                    for (int g = 0; g < 2; g++) {
                        const int qr = qrow0 + 16 * g + l15;
#pragma unroll
                        for (int rg = 0; rg < 4; rg++)
                            if (kvb + nt * 16 + rg > qr) St[nt][g][rg] = -__builtin_inff();
                    }
            }

            // ---- online softmax (exp2 domain) + P pack (per qcol group g) ----
            unsigned int pk[2][4][2];
#pragma unroll
            for (int g = 0; g < 2; g++) {
                float mt = -__builtin_inff();
#pragma unroll
                for (int nt = 0; nt < 4; nt++) {
                    mt = fmaxf(mt, fmaxf(fmaxf(St[nt][g][0], St[nt][g][1]),
                                         fmaxf(St[nt][g][2], St[nt][g][3])));
                }
                mt = fmaxf(mt, __shfl_xor(mt, 16));
                mt = fmaxf(mt, __shfl_xor(mt, 32));
                const float mn = fmaxf(m_s[g], mt);
                const float alpha = exp2f(m_s[g] - mn);
                m_s[g] = mn;
                float rs = 0.f;
#pragma unroll
                for (int nt = 0; nt < 4; nt++) {
#pragma unroll
                    for (int rg = 0; rg < 4; rg++) {
                        const float pp = exp2f(St[nt][g][rg] - mn);
                        St[nt][g][rg] = pp;
                        rs += pp;
                    }
                    pk[g][nt][0] = packbf2(St[nt][g][0], St[nt][g][1]);
                    pk[g][nt][1] = packbf2(St[nt][g][2], St[nt][g][3]);
                }
                rs += __shfl_xor(rs, 16);
                rs += __shfl_xor(rs, 32);
                l_s[g] = l_s[g] * alpha + rs;
                if (!__all(alpha == 1.f)) {
#pragma unroll
                    for (int nt = 0; nt < 4; nt++)
#pragma unroll
                        for (int rg = 0; rg < 4; rg++) O[nt][g][rg] *= alpha;
                }
            }

            // ---- P^T B-fragments via shuffles; O^T += V^T P^T : 16 MFMA ----
#pragma unroll
            for (int g = 0; g < 2; g++)
#pragma unroll
                for (int c = 0; c < 2; c++) {
                    int4v bd;
#pragma unroll
                    for (int d = 0; d < 4; d++) {
                        const int src = (quad & 1) * 32 + (d >> 1) * 16 + l15;
                        const int v0 = __shfl((int)pk[g][2 * c][d & 1], src);
                        const int v1 = __shfl((int)pk[g][2 * c + 1][d & 1], src);
                        bd[d] = (quad & 2) ? v1 : v0;
                    }
                    const short8 pb = __builtin_bit_cast(short8, bd);
#pragma unroll
                    for (int nt = 0; nt < 4; nt++)
                        O[nt][g] = mfma16(VA[nt][c], pb, O[nt][g]);
                }
        }

        // ---- epilogue: per-wave LDS transpose O^T -> [qrow][a], store bf16.
        //      tr slice is wave-private: no barrier needed (same-wave dep). ----
#pragma unroll
        for (int nt = 0; nt < 4; nt++)
#pragma unroll
            for (int g = 0; g < 2; g++)
#pragma unroll
                for (int rg = 0; rg < 4; rg++)
                    tw[(16 * g + l15) * 72 + nt * 16 + quad * 4 + rg] = f2bf(O[nt][g][rg]);

        {
            const size_t unit = ((size_t)(b * 128 + qt32) * (size_t)S + s);
            unsigned short* ob = Opart + unit * 2048;
            const int row = lane >> 1;
#pragma unroll
            for (int pp = 0; pp < 4; pp++) {
                const int colh = (lane & 1) * 8 + pp * 16;
                *(short8*)(ob + row * 64 + colh) = *(const short8*)&tw[row * 72 + colh];
            }
            if (quad == 0) {
                float* mlb = ml + unit * 64;
#pragma unroll
                for (int g = 0; g < 2; g++) {
                    mlb[16 * g + l15]      = m_s[g];
                    mlb[32 + 16 * g + l15] = l_s[g];
                }
            }
        }
    }
}

// ---------------------------------------------------------------------------
// Kernel 3: merge the S kv-stripe partials -> out fp32 [b][t][a].
// grid (128, 4): per (b, qt32).  Thread: qrow = tid>>3, a8 = (tid&7)*8.
// ---------------------------------------------------------------------------
__global__ __launch_bounds__(256) void merge_kernel(
    const unsigned short* __restrict__ Opart, const float* __restrict__ ml,
    float* __restrict__ out, int S)
{
    const int qt32 = blockIdx.x, b = blockIdx.y;
    const int tid  = threadIdx.x;
    const int qr   = tid >> 3;           // 0..31
    const int a8   = (tid & 7) * 8;
    const size_t ub = (size_t)(b * 128 + qt32) * (size_t)S;

    float mstar = -__builtin_inff();
    for (int s = 0; s < S; s++)
        mstar = fmaxf(mstar, ml[(ub + s) * 64 + qr]);

    float acc[8];
#pragma unroll
    for (int j = 0; j < 8; j++) acc[j] = 0.f;
    float lsum = 0.f;

    for (int s = 0; s < S; s++) {
        const float ms = ml[(ub + s) * 64 + qr];
        const float ls = ml[(ub + s) * 64 + 32 + qr];
        const float w  = exp2f(ms - mstar);
        lsum += ls * w;
        const short8 ov = *(const short8*)&Opart[(ub + s) * 2048 + qr * 64 + a8];
#pragma unroll
        for (int j = 0; j < 8; j++) acc[j] += w * bf2f((unsigned short)ov[j]);
    }
    const float inv = 1.f / lsum;
    float* op = out + (((size_t)b << 12) + qt32 * 32 + qr) * An + a8;
    float4 r0 = {acc[0] * inv, acc[1] * inv, acc[2] * inv, acc[3] * inv};
    float4 r1 = {acc[4] * inv, acc[5] * inv, acc[6] * inv, acc[7] * inv};
    *(float4*)op       = r0;
    *(float4*)(op + 4) = r1;
}

// ---------------------------------------------------------------------------
extern "C" void kernel_launch(void* const* d_in, const int* in_sizes, int n_in,
                              void* d_out, int out_size, void* d_ws, size_t ws_size,
                              hipStream_t stream) {
    const float* emb = (const float*)d_in[0];
    const float* Wk  = (const float*)d_in[1];
    const float* bk  = (const float*)d_in[2];
    const float* Wq  = (const float*)d_in[3];
    const float* bq  = (const float*)d_in[4];
    const float* Wv  = (const float*)d_in[5];
    const float* bv  = (const float*)d_in[6];
    float* out = (float*)d_out;

    char* ws = (char*)d_ws;
    const size_t MB = 1024 * 1024;

    // pick stripe count S from available workspace (prefer more parallelism)
    int S = 1, lgS = 0;
    for (int cand = 16; cand >= 1; cand >>= 1) {
        const size_t need = 6 * MB + 128 * 1024                  // q,k,v_t,W_t
                          + (size_t)cand * 128 * 1024            // ml
                          + (size_t)cand * 2 * MB;               // Opart
        if (need <= ws_size) {
            S = cand;
            lgS = (cand == 16) ? 4 : (cand == 8) ? 3 : (cand == 4) ? 2 : (cand == 2) ? 1 : 0;
            break;
        }
    }

    unsigned short* q     = (unsigned short*)(ws);                         // 2 MB
    unsigned short* k     = (unsigned short*)(ws + 2 * MB);                // 2 MB
    unsigned short* v_t   = (unsigned short*)(ws + 4 * MB);                // 2 MB
    unsigned short* W_t   = (unsigned short*)(ws + 6 * MB);                // 96 KB
    float*          ml    = (float*)(ws + 6 * MB + 128 * 1024);            // S*128 KB
    unsigned short* Opart = (unsigned short*)(ws + 6 * MB + 128 * 1024 + (size_t)S * 128 * 1024);

    prep_kernel<<<dim3(3, 16), 256, 0, stream>>>(Wq, Wk, Wv, W_t);
    proj_kernel<<<512, 256, 0, stream>>>(emb, W_t, bq, bk, bv, q, k, v_t);
    flash_kernel<<<dim3(16 * S, 4), 256, 0, stream>>>(q, k, v_t, Opart, ml, S, lgS);
    merge_kernel<<<dim3(128, 4), 256, 0, stream>>>(Opart, ml, out, S);
}

// Round 5
// 144.665 us; speedup vs baseline: 1.0497x; 1.0497x over previous
//
#include <hip/hip_runtime.h>
#include <math.h>

#define Bn 4
#define Tn 4096
#define En 256
#define An 64

typedef __attribute__((ext_vector_type(8))) short short8;
typedef __attribute__((ext_vector_type(8))) __bf16 bf16x8;
typedef __attribute__((ext_vector_type(4))) float f32x4;
typedef __attribute__((ext_vector_type(4))) int int4v;
typedef __attribute__((ext_vector_type(4))) short short4v;

__device__ __forceinline__ f32x4 mfma16(short8 a, short8 b, f32x4 c) {
    return __builtin_amdgcn_mfma_f32_16x16x32_bf16(
        __builtin_bit_cast(bf16x8, a), __builtin_bit_cast(bf16x8, b), c, 0, 0, 0);
}
__device__ __forceinline__ unsigned short f2bf(float x) {   // RNE fp32->bf16
    unsigned int u = __builtin_bit_cast(unsigned int, x);
    u += 0x7fffu + ((u >> 16) & 1u);
    return (unsigned short)(u >> 16);
}
__device__ __forceinline__ float bf2f(unsigned short h) {
    return __builtin_bit_cast(float, (unsigned int)h << 16);
}
__device__ __forceinline__ unsigned int packbf2(float lo, float hi) {
    return (unsigned int)f2bf(lo) | ((unsigned int)f2bf(hi) << 16);
}

// ---------------------------------------------------------------------------
// Kernel 0: transpose W[e][a] fp32 -> W_t[m][a][e] bf16.  grid (3, 16).
// ---------------------------------------------------------------------------
__global__ __launch_bounds__(256) void prep_kernel(
    const float* __restrict__ Wq, const float* __restrict__ Wk, const float* __restrict__ Wv,
    unsigned short* __restrict__ W_t)
{
    const int m  = blockIdx.x;
    const int es = blockIdx.y;          // e-slice of 16
    const float* __restrict__ W = (m == 0) ? Wq : (m == 1 ? Wk : Wv);
    __shared__ unsigned short tr[64][18];
    const int tid = threadIdx.x;
    {
        const int e_l = tid >> 4;             // 0..15
        const int a4  = (tid & 15) * 4;
        float4 w = *(const float4*)&W[(size_t)(es * 16 + e_l) * An + a4];
        tr[a4 + 0][e_l] = f2bf(w.x);
        tr[a4 + 1][e_l] = f2bf(w.y);
        tr[a4 + 2][e_l] = f2bf(w.z);
        tr[a4 + 3][e_l] = f2bf(w.w);
    }
    __syncthreads();
    {
        const int a  = tid >> 2;              // 0..63
        const int eo = (tid & 3) * 4;         // 0..12
        short4v v = { (short)tr[a][eo], (short)tr[a][eo + 1],
                      (short)tr[a][eo + 2], (short)tr[a][eo + 3] };
        *(short4v*)&W_t[(size_t)(m * 64 + a) * En + es * 16 + eo] = v;
    }
}

// ---------------------------------------------------------------------------
// Kernel 1: fused QKV projection, bf16 MFMA.  grid 512: blockIdx.x>>1 = 64-row
// block, &1 = column half (6 n-tiles each).  Wave w owns rows w*16..+15.
// Outputs: q bf16 [b][t][a] pre-scaled by 0.125*log2(e)  (exp2-domain softmax),
//          k bf16 [b][t][a],  v_t bf16 [b][a][t].
// ---------------------------------------------------------------------------
__global__ __launch_bounds__(256, 2) void proj_kernel(
    const float* __restrict__ emb, const unsigned short* __restrict__ W_t,
    const float* __restrict__ bq, const float* __restrict__ bk, const float* __restrict__ bv,
    unsigned short* __restrict__ q, unsigned short* __restrict__ k, unsigned short* __restrict__ v_t)
{
    const int tid  = threadIdx.x;
    const int wave = tid >> 6, lane = tid & 63, quad = lane >> 4, l15 = lane & 15;
    const int rb    = blockIdx.x >> 1;
    const int half  = blockIdx.x & 1;
    const int row0  = rb * 64;              // global row in [0, B*T)
    const int b     = row0 >> 12;
    const int trow0 = row0 & 4095;

    __shared__ unsigned short vtr[64 * 72];

    // A-fragments: emb rows (fp32 -> bf16), A[m=l15][k=quad*8+j]
    short8 A[8];
    {
        const float* erow = emb + (size_t)(row0 + wave * 16 + l15) * En;
#pragma unroll
        for (int c = 0; c < 8; c++) {
            const float* p = erow + c * 32 + quad * 8;
            float4 f0 = *(const float4*)p;
            float4 f1 = *(const float4*)(p + 4);
            A[c] = (short8){(short)f2bf(f0.x), (short)f2bf(f0.y), (short)f2bf(f0.z), (short)f2bf(f0.w),
                            (short)f2bf(f1.x), (short)f2bf(f1.y), (short)f2bf(f1.z), (short)f2bf(f1.w)};
        }
    }

    f32x4 acc[6];
#pragma unroll
    for (int i = 0; i < 6; i++) acc[i] = (f32x4){0.f, 0.f, 0.f, 0.f};

#pragma unroll
    for (int i = 0; i < 6; i++) {
        const int nt = half * 6 + i;
        const unsigned short* wb =
            W_t + (size_t)((nt >> 2) * 64 + (nt & 3) * 16 + l15) * En + quad * 8;
#pragma unroll
        for (int c = 0; c < 8; c++) {
            short8 bf = *(const short8*)(wb + c * 32);
            acc[i] = mfma16(A[c], bf, acc[i]);
        }
    }

    const float QS = 0.125f * 1.4426950408889634f;   // 1/sqrt(A) * log2(e)
#pragma unroll
    for (int i = 0; i < 6; i++) {
        const int nt = half * 6 + i;
        const int m  = nt >> 2;
        const int al = (nt & 3) * 16 + l15;
        const float bsv = ((m == 0) ? bq : (m == 1) ? bk : bv)[al];
#pragma unroll
        for (int rg = 0; rg < 4; rg++) {
            const int row_l = wave * 16 + quad * 4 + rg;   // C/D: row=quad*4+reg, col=l15
            const float val = acc[i][rg] + bsv;
            if (m == 0)      q[(size_t)(row0 + row_l) * An + al] = f2bf(val * QS);
            else if (m == 1) k[(size_t)(row0 + row_l) * An + al] = f2bf(val);
            else             vtr[al * 72 + row_l] = f2bf(val);
        }
    }
    if (half == 1) {
        __syncthreads();
        // flush V^T tile: v_t[b][a][t]
        const int a  = tid >> 2;
        const int tg = (tid & 3) * 16;
        unsigned short* dst = v_t + (size_t)(b * 64 + a) * Tn + trow0 + tg;
        *(short8*)dst       = *(const short8*)&vtr[a * 72 + tg];
        *(short8*)(dst + 8) = *(const short8*)&vtr[a * 72 + tg + 8];
    }
}

// ---------------------------------------------------------------------------
// K/V fragment double-buffer for the flash K-loop.
// ---------------------------------------------------------------------------
struct KVbuf { short8 KA[4][2]; short8 VA[4][2]; };

// ---------------------------------------------------------------------------
// Kernel 2: flash attention, bf16 MFMA.  NO barriers; waves independent, all
// EQUAL LENGTH (complementary pair p,127-p), kv-striped by S, and now
// SOFTWARE-PIPELINED: iteration t issues the loads for t+S before computing,
// so the K/V fragment latency is hidden behind a full iteration of compute.
// grid (16*S, 4).  wu = blockIdx.x*4+wave: p = wu>>lgS, s = wu&(S-1).
// ---------------------------------------------------------------------------
__global__ __launch_bounds__(256, 2) void flash_kernel(
    const unsigned short* __restrict__ q, const unsigned short* __restrict__ k,
    const unsigned short* __restrict__ v_t,
    unsigned short* __restrict__ Opart, float* __restrict__ ml,
    int S, int lgS)
{
    const int b    = blockIdx.y;
    const int tid  = threadIdx.x;
    const int wave = tid >> 6, lane = tid & 63, quad = lane >> 4, l15 = lane & 15;
    const int wu   = blockIdx.x * 4 + wave;
    const int p    = wu >> lgS;
    const int s    = wu & (S - 1);

    __shared__ unsigned short tr[4][32 * 72];   // per-wave O transpose scratch
    unsigned short* tw = tr[wave];

    const unsigned short* kb0 = k   + ((size_t)b << 12) * An;
    const unsigned short* vb0 = v_t + (size_t)b * An * Tn;

    // loop-invariant per-lane offsets for the fragment gathers
    int koff[4][2], voff[4][2];
#pragma unroll
    for (int nt = 0; nt < 4; nt++)
#pragma unroll
        for (int c = 0; c < 2; c++) {
            koff[nt][c] = (nt * 16 + l15) * An + c * 32 + quad * 8;
            voff[nt][c] = (nt * 16 + l15) * Tn + c * 32 + quad * 8;
        }

#pragma unroll 1
    for (int tile = 0; tile < 2; tile++) {
        const int qt32  = tile ? (127 - p) : p;
        const int qrow0 = qt32 * 32;
        const int tmax  = qt32 >> 1;

        // persistent Q B-fragments: B[k=a][n=qrow], group g = qcols 16g..16g+15
        short8 qB[2][2];
        {
            const unsigned short* qb = q + (((size_t)b << 12) + qrow0) * An;
#pragma unroll
            for (int g = 0; g < 2; g++)
#pragma unroll
                for (int c = 0; c < 2; c++)
                    qB[g][c] = *(const short8*)(qb + (size_t)(16 * g + l15) * An + c * 32 + quad * 8);
        }

        float m_s[2] = {-__builtin_inff(), -__builtin_inff()};
        float l_s[2] = {0.f, 0.f};
        f32x4 O[4][2];
#pragma unroll
        for (int nt = 0; nt < 4; nt++)
#pragma unroll
            for (int g = 0; g < 2; g++) O[nt][g] = (f32x4){0.f, 0.f, 0.f, 0.f};

        // ---- fragment load (no wait until first use) ----
        auto load_kv = [&](KVbuf& buf, int t) {
            const unsigned short* kb = kb0 + (size_t)t * (64 * An);
            const unsigned short* vb = vb0 + (size_t)t * 64;
#pragma unroll
            for (int nt = 0; nt < 4; nt++)
#pragma unroll
                for (int c = 0; c < 2; c++) {
                    buf.KA[nt][c] = *(const short8*)(kb + koff[nt][c]);
                    buf.VA[nt][c] = *(const short8*)(vb + voff[nt][c]);
                }
        };

        // ---- one 64-kv iteration using pre-loaded fragments ----
        auto body = [&](int t, const KVbuf& kv) {
            // S^T = K Q^T : 16 MFMA.  S^T[kv=quad*4+rg(+16nt)][qrow=16g+l15]
            f32x4 St[4][2];
#pragma unroll
            for (int nt = 0; nt < 4; nt++)
#pragma unroll
                for (int g = 0; g < 2; g++) {
                    f32x4 acc = (f32x4){0.f, 0.f, 0.f, 0.f};
                    acc = mfma16(kv.KA[nt][0], qB[g][0], acc);
                    acc = mfma16(kv.KA[nt][1], qB[g][1], acc);
                    St[nt][g] = acc;
                }

            // causal mask on the diagonal tile
            if (t == tmax) {
                const int kvb = t * 64 + quad * 4;
#pragma unroll
                for (int nt = 0; nt < 4; nt++)
#pragma unroll
                    for (int g = 0; g < 2; g++) {
                        const int qr = qrow0 + 16 * g + l15;
#pragma unroll
                        for (int rg = 0; rg < 4; rg++)
                            if (kvb + nt * 16 + rg > qr) St[nt][g][rg] = -__builtin_inff();
                    }
            }

            // online softmax (exp2 domain) + P pack
            unsigned int pk[2][4][2];
#pragma unroll
            for (int g = 0; g < 2; g++) {
                float mt = -__builtin_inff();
#pragma unroll
                for (int nt = 0; nt < 4; nt++) {
                    mt = fmaxf(mt, fmaxf(fmaxf(St[nt][g][0], St[nt][g][1]),
                                         fmaxf(St[nt][g][2], St[nt][g][3])));
                }
                mt = fmaxf(mt, __shfl_xor(mt, 16));
                mt = fmaxf(mt, __shfl_xor(mt, 32));
                const float mn = fmaxf(m_s[g], mt);
                const float alpha = exp2f(m_s[g] - mn);
                m_s[g] = mn;
                float rs = 0.f;
#pragma unroll
                for (int nt = 0; nt < 4; nt++) {
#pragma unroll
                    for (int rg = 0; rg < 4; rg++) {
                        const float pp = exp2f(St[nt][g][rg] - mn);
                        St[nt][g][rg] = pp;
                        rs += pp;
                    }
                    pk[g][nt][0] = packbf2(St[nt][g][0], St[nt][g][1]);
                    pk[g][nt][1] = packbf2(St[nt][g][2], St[nt][g][3]);
                }
                rs += __shfl_xor(rs, 16);
                rs += __shfl_xor(rs, 32);
                l_s[g] = l_s[g] * alpha + rs;
                if (!__all(alpha == 1.f)) {
#pragma unroll
                    for (int nt = 0; nt < 4; nt++)
#pragma unroll
                        for (int rg = 0; rg < 4; rg++) O[nt][g][rg] *= alpha;
                }
            }

            // P^T B-fragments via shuffles; O^T += V^T P^T : 16 MFMA
#pragma unroll
            for (int g = 0; g < 2; g++)
#pragma unroll
                for (int c = 0; c < 2; c++) {
                    int4v bd;
#pragma unroll
                    for (int d = 0; d < 4; d++) {
                        const int src = (quad & 1) * 32 + (d >> 1) * 16 + l15;
                        const int v0 = __shfl((int)pk[g][2 * c][d & 1], src);
                        const int v1 = __shfl((int)pk[g][2 * c + 1][d & 1], src);
                        bd[d] = (quad & 2) ? v1 : v0;
                    }
                    const short8 pb = __builtin_bit_cast(short8, bd);
#pragma unroll
                    for (int nt = 0; nt < 4; nt++)
                        O[nt][g] = mfma16(kv.VA[nt][c], pb, O[nt][g]);
                }
        };

        // ---- software-pipelined K-loop (ping-pong buffers) ----
        {
            int t = s;
            if (t <= tmax) {
                KVbuf bufA, bufB;
                load_kv(bufA, t);
                for (;;) {
                    int tn = t + S;
                    bool more = (tn <= tmax);
                    if (more) load_kv(bufB, tn);
                    body(t, bufA);
                    if (!more) break;
                    t = tn;
                    tn = t + S;
                    more = (tn <= tmax);
                    if (more) load_kv(bufA, tn);
                    body(t, bufB);
                    if (!more) break;
                    t = tn;
                }
            }
        }

        // ---- epilogue: per-wave LDS transpose O^T -> [qrow][a], store bf16.
        //      tr slice is wave-private: no barrier needed (same-wave dep). ----
#pragma unroll
        for (int nt = 0; nt < 4; nt++)
#pragma unroll
            for (int g = 0; g < 2; g++)
#pragma unroll
                for (int rg = 0; rg < 4; rg++)
                    tw[(16 * g + l15) * 72 + nt * 16 + quad * 4 + rg] = f2bf(O[nt][g][rg]);

        {
            const size_t unit = ((size_t)(b * 128 + qt32) * (size_t)S + s);
            unsigned short* ob = Opart + unit * 2048;
            const int row = lane >> 1;
#pragma unroll
            for (int pp = 0; pp < 4; pp++) {
                const int colh = (lane & 1) * 8 + pp * 16;
                *(short8*)(ob + row * 64 + colh) = *(const short8*)&tw[row * 72 + colh];
            }
            if (quad == 0) {
                float* mlb = ml + unit * 64;
#pragma unroll
                for (int g = 0; g < 2; g++) {
                    mlb[16 * g + l15]      = m_s[g];
                    mlb[32 + 16 * g + l15] = l_s[g];
                }
            }
        }
    }
}

// ---------------------------------------------------------------------------
// Kernel 3: merge the S kv-stripe partials -> out fp32 [b][t][a].
// grid (128, 4): per (b, qt32).  Thread: qrow = tid>>3, a8 = (tid&7)*8.
// ---------------------------------------------------------------------------
__global__ __launch_bounds__(256) void merge_kernel(
    const unsigned short* __restrict__ Opart, const float* __restrict__ ml,
    float* __restrict__ out, int S)
{
    const int qt32 = blockIdx.x, b = blockIdx.y;
    const int tid  = threadIdx.x;
    const int qr   = tid >> 3;           // 0..31
    const int a8   = (tid & 7) * 8;
    const size_t ub = (size_t)(b * 128 + qt32) * (size_t)S;

    float mstar = -__builtin_inff();
    for (int s = 0; s < S; s++)
        mstar = fmaxf(mstar, ml[(ub + s) * 64 + qr]);

    float acc[8];
#pragma unroll
    for (int j = 0; j < 8; j++) acc[j] = 0.f;
    float lsum = 0.f;

    for (int s = 0; s < S; s++) {
        const float ms = ml[(ub + s) * 64 + qr];
        const float ls = ml[(ub + s) * 64 + 32 + qr];
        const float w  = exp2f(ms - mstar);
        lsum += ls * w;
        const short8 ov = *(const short8*)&Opart[(ub + s) * 2048 + qr * 64 + a8];
#pragma unroll
        for (int j = 0; j < 8; j++) acc[j] += w * bf2f((unsigned short)ov[j]);
    }
    const float inv = 1.f / lsum;
    float* op = out + (((size_t)b << 12) + qt32 * 32 + qr) * An + a8;
    float4 r0 = {acc[0] * inv, acc[1] * inv, acc[2] * inv, acc[3] * inv};
    float4 r1 = {acc[4] * inv, acc[5] * inv, acc[6] * inv, acc[7] * inv};
    *(float4*)op       = r0;
    *(float4*)(op + 4) = r1;
}

// ---------------------------------------------------------------------------
extern "C" void kernel_launch(void* const* d_in, const int* in_sizes, int n_in,
                              void* d_out, int out_size, void* d_ws, size_t ws_size,
                              hipStream_t stream) {
    const float* emb = (const float*)d_in[0];
    const float* Wk  = (const float*)d_in[1];
    const float* bk  = (const float*)d_in[2];
    const float* Wq  = (const float*)d_in[3];
    const float* bq  = (const float*)d_in[4];
    const float* Wv  = (const float*)d_in[5];
    const float* bv  = (const float*)d_in[6];
    float* out = (float*)d_out;

    char* ws = (char*)d_ws;
    const size_t MB = 1024 * 1024;

    // pick stripe count S from available workspace.  S=8: 512 blocks = 2/CU,
    // equal-length waves, and merge traffic stays moderate (Opart 16 MB).
    int S = 1, lgS = 0;
    for (int cand = 8; cand >= 1; cand >>= 1) {
        const size_t need = 6 * MB + 128 * 1024                  // q,k,v_t,W_t
                          + (size_t)cand * 128 * 1024            // ml
                          + (size_t)cand * 2 * MB;               // Opart
        if (need <= ws_size) {
            S = cand;
            lgS = (cand == 8) ? 3 : (cand == 4) ? 2 : (cand == 2) ? 1 : 0;
            break;
        }
    }

    unsigned short* q     = (unsigned short*)(ws);                         // 2 MB
    unsigned short* k     = (unsigned short*)(ws + 2 * MB);                // 2 MB
    unsigned short* v_t   = (unsigned short*)(ws + 4 * MB);                // 2 MB
    unsigned short* W_t   = (unsigned short*)(ws + 6 * MB);                // 96 KB
    float*          ml    = (float*)(ws + 6 * MB + 128 * 1024);            // S*128 KB
    unsigned short* Opart = (unsigned short*)(ws + 6 * MB + 128 * 1024 + (size_t)S * 128 * 1024);

    prep_kernel<<<dim3(3, 16), 256, 0, stream>>>(Wq, Wk, Wv, W_t);
    proj_kernel<<<512, 256, 0, stream>>>(emb, W_t, bq, bk, bv, q, k, v_t);
    flash_kernel<<<dim3(16 * S, 4), 256, 0, stream>>>(q, k, v_t, Opart, ml, S, lgS);
    merge_kernel<<<dim3(128, 4), 256, 0, stream>>>(Opart, ml, out, S);
}